// Round 3
// baseline (371.785 us; speedup 1.0000x reference)
//
#include <hip/hip_runtime.h>
#include <math.h>

#define Nn 512
#define Tt 8
#define Ee 16384
#define NNc (Nn*Nn)          // 262144
#define TNr (Tt*Nn)          // 4096
#define TE  (Tt*Ee)          // 131072

// ---------------- feat_proj: [T*N,128] -> relu -> [.,256] -> relu -> [.,64] ; concat noise -> emb[.,80]
__global__ __launch_bounds__(256) void k_featproj(
    const float* __restrict__ feats, const float* __restrict__ noise,
    const float* __restrict__ Wp1, const float* __restrict__ bp1,
    const float* __restrict__ Wp2, const float* __restrict__ bp2,
    float* __restrict__ emb)
{
    __shared__ float sfeat[16][128];
    __shared__ float sh1[16][256];
    int tid = threadIdx.x;
    int r0 = blockIdx.x * 16;
#pragma unroll
    for (int k = 0; k < 8; ++k) {
        int lin = k*256 + tid;
        sfeat[lin>>7][lin&127] = feats[(size_t)r0*128 + lin];
    }
    __syncthreads();
    {
        int j = tid;
        float acc[16];
#pragma unroll
        for (int r=0;r<16;++r) acc[r]=0.f;
        for (int i=0;i<128;i+=4) {
            float w0=Wp1[(i+0)*256+j], w1=Wp1[(i+1)*256+j];
            float w2=Wp1[(i+2)*256+j], w3=Wp1[(i+3)*256+j];
#pragma unroll
            for (int r=0;r<16;++r) {
                float4 f = *(const float4*)&sfeat[r][i];
                acc[r] += f.x*w0 + f.y*w1 + f.z*w2 + f.w*w3;
            }
        }
        float b = bp1[j];
#pragma unroll
        for (int r=0;r<16;++r) sh1[r][j] = fmaxf(acc[r]+b, 0.f);
    }
    __syncthreads();
    {
        int jo = tid & 63;
        int rr = tid >> 6;
        float b2v = bp2[jo];
        for (int rg=0; rg<4; ++rg) {
            int r = rg*4 + rr;
            float a2 = 0.f;
            for (int i=0;i<256;i+=4) {
                float4 f = *(const float4*)&sh1[r][i];
                a2 += f.x*Wp2[(i+0)*64+jo] + f.y*Wp2[(i+1)*64+jo]
                    + f.z*Wp2[(i+2)*64+jo] + f.w*Wp2[(i+3)*64+jo];
            }
            emb[(size_t)(r0+r)*80 + jo] = fmaxf(a2+b2v, 0.f);
        }
    }
    {
        int r = tid>>4, k = tid&15;
        emb[(size_t)(r0+r)*80 + 64 + k] = noise[(size_t)(r0+r)*16 + k];
    }
}

// ---------------- hh = relu(emb @ W1[80,128] + b1)
__global__ __launch_bounds__(256) void k_wle1(
    const float* __restrict__ emb, const float* __restrict__ W1,
    const float* __restrict__ b1, float* __restrict__ hh)
{
    __shared__ float semb[16][80];
    int tid = threadIdx.x;
    int r0 = blockIdx.x*16;
#pragma unroll
    for (int k=0;k<5;++k) {
        int lin = k*256+tid;
        semb[lin/80][lin%80] = emb[(size_t)r0*80 + lin];
    }
    __syncthreads();
    int j = tid & 127;
    int rb = (tid>>7)*8;
    float acc[8];
#pragma unroll
    for (int r=0;r<8;++r) acc[r]=0.f;
    for (int i=0;i<80;i+=4) {
        float w0=W1[(i+0)*128+j], w1=W1[(i+1)*128+j];
        float w2=W1[(i+2)*128+j], w3=W1[(i+3)*128+j];
#pragma unroll
        for (int r=0;r<8;++r) {
            float4 f = *(const float4*)&semb[rb+r][i];
            acc[r] += f.x*w0 + f.y*w1 + f.z*w2 + f.w*w3;
        }
    }
    float b = b1[j];
#pragma unroll
    for (int r=0;r<8;++r) hh[(size_t)(r0+rb+r)*128 + j] = fmaxf(acc[r]+b, 0.f);
}

// ---------------- msg scatter: agg[dst] += ew * hh[src]
__global__ __launch_bounds__(256) void k_scatter(
    const int* __restrict__ ei, const float* __restrict__ ew,
    const float* __restrict__ hh, float* __restrict__ agg)
{
    size_t g = (size_t)blockIdx.x*256 + threadIdx.x;   // < T*E*128
    int ch = (int)(g & 127);
    int eg = (int)(g >> 7);        // t*E+e
    int t = eg >> 14;
    int e = eg & (Ee-1);
    int dst = ei[t*2*Ee + e];
    int src = ei[t*2*Ee + Ee + e];
    float w = ew[eg];
    float v = w * hh[((size_t)(t*Nn+src))*128 + ch];
    atomicAdd(&agg[((size_t)(t*Nn+dst))*128 + ch], v);
}

// ---------------- h2 = relu((hh+agg) @ W2[128,128] + b2)
__global__ __launch_bounds__(256) void k_wle2(
    const float* __restrict__ hh, const float* __restrict__ agg,
    const float* __restrict__ W2, const float* __restrict__ b2,
    float* __restrict__ h2)
{
    __shared__ float sx[16][128];
    int tid=threadIdx.x; int r0=blockIdx.x*16;
#pragma unroll
    for (int k=0;k<8;++k){
        int lin=k*256+tid;
        size_t gidx=(size_t)r0*128+lin;
        sx[lin>>7][lin&127]=hh[gidx]+agg[gidx];
    }
    __syncthreads();
    int j=tid&127; int rb=(tid>>7)*8;
    float acc[8];
#pragma unroll
    for(int r=0;r<8;++r)acc[r]=0.f;
    for(int i=0;i<128;i+=4){
        float w0=W2[(i+0)*128+j], w1=W2[(i+1)*128+j];
        float w2v=W2[(i+2)*128+j], w3=W2[(i+3)*128+j];
#pragma unroll
        for(int r=0;r<8;++r){
            float4 f=*(const float4*)&sx[rb+r][i];
            acc[r]+=f.x*w0+f.y*w1+f.z*w2v+f.w*w3;
        }
    }
    float b=b2[j];
#pragma unroll
    for(int r=0;r<8;++r) h2[(size_t)(r0+rb+r)*128+j]=fmaxf(acc[r]+b,0.f);
}

// ---------------- transpose W3 [128][128] -> w3t [j][i]
__global__ __launch_bounds__(256) void k_w3t(
    const float* __restrict__ W3, float* __restrict__ w3t)
{
    int lin = blockIdx.x*256 + threadIdx.x;   // < 16384
    int i = lin >> 7, j = lin & 127;
    w3t[j*128 + i] = W3[lin];
}

// ---------------- edge scores: s = relu((h2[a]*h2[b]) @ W3) . w4 + b4
// One edge per thread: ef[128] in registers; W3T rows read with wave-uniform
// addresses directly from global -> compiler scalarizes to s_load via K$,
// freeing the LDS pipe entirely (which was the 160us bottleneck).
__global__ __launch_bounds__(256, 3) void k_edge3(
    const int* __restrict__ ei, const float* __restrict__ h2,
    const float* __restrict__ w3t, const float* __restrict__ b3,
    const float* __restrict__ w4, const float* __restrict__ b4,
    float* __restrict__ sc)
{
    int tid = threadIdx.x;
    int eg = blockIdx.x*256 + tid;            // < TE
    int t = eg >> 14, e = eg & (Ee-1);
    int a = ei[t*2*Ee + e], b = ei[t*2*Ee + Ee + e];
    const float4* __restrict__ pa = (const float4*)&h2[((size_t)(t*Nn+a))*128];
    const float4* __restrict__ pb = (const float4*)&h2[((size_t)(t*Nn+b))*128];

    float4 ef[32];
#pragma unroll
    for (int k=0;k<32;++k){
        float4 x = pa[k], y = pb[k];
        x.x*=y.x; x.y*=y.y; x.z*=y.z; x.w*=y.w;
        ef[k] = x;
    }

    float s = b4[0];
#pragma unroll 2
    for (int j=0;j<128;++j){
        const float4* __restrict__ w = (const float4*)&w3t[j*128]; // uniform addr
        float a0=0.f,a1=0.f,a2=0.f,a3=0.f;
#pragma unroll
        for (int k=0;k<32;k+=4){
            float4 w0=w[k], w1=w[k+1], w2=w[k+2], w3v=w[k+3];
            a0 += ef[k  ].x*w0.x + ef[k  ].y*w0.y + ef[k  ].z*w0.z + ef[k  ].w*w0.w;
            a1 += ef[k+1].x*w1.x + ef[k+1].y*w1.y + ef[k+1].z*w1.z + ef[k+1].w*w1.w;
            a2 += ef[k+2].x*w2.x + ef[k+2].y*w2.y + ef[k+2].z*w2.z + ef[k+2].w*w2.w;
            a3 += ef[k+3].x*w3v.x + ef[k+3].y*w3v.y + ef[k+3].z*w3v.z + ef[k+3].w*w3v.w;
        }
        float acc = (a0+a1)+(a2+a3);
        s += fmaxf(acc + b3[j], 0.f) * w4[j];
    }
    sc[eg] = s;
}

// ---------------- densify with last-write-wins: tag pass then write pass
__global__ __launch_bounds__(256) void k_tag(const int* __restrict__ ei, int* __restrict__ tag)
{
    int g = blockIdx.x*256+threadIdx.x;        // < T*E
    int t = g>>14, e = g&(Ee-1);
    int a = ei[t*2*Ee + e], b = ei[t*2*Ee + Ee + e];
    atomicMax(&tag[t*NNc + a*Nn + b], g+1);
}

__global__ __launch_bounds__(256) void k_dense(
    const int* __restrict__ ei, const float* __restrict__ sc,
    const int* __restrict__ tag, float* __restrict__ dense)
{
    int g = blockIdx.x*256+threadIdx.x;
    int t = g>>14, e = g&(Ee-1);
    int a = ei[t*2*Ee + e], b = ei[t*2*Ee + Ee + e];
    int cell = t*NNc + a*Nn + b;
    if (tag[cell] == g+1) dense[cell] = sc[g];
}

// ---------------- SSM recurrence: only cells with an edge at t=T-1 have nonzero output
__global__ __launch_bounds__(256) void k_ssm(
    const int* __restrict__ ei, const float* __restrict__ dense,
    const float* __restrict__ W_in, const float* __restrict__ conv_w,
    const float* __restrict__ conv_b, const float* __restrict__ dt_bias,
    const float* __restrict__ A_log, const float* __restrict__ D_skip,
    const float* __restrict__ W_out, float* __restrict__ out)
{
    __shared__ float scw[132], scb[33], swin[35];
    int tid = threadIdx.x;
    if (tid < 132) scw[tid] = conv_w[tid];
    if (tid < 33)  scb[tid] = conv_b[tid];
    if (tid < 35)  swin[tid] = W_in[tid];
    __syncthreads();

    int e = blockIdx.x*256 + tid;              // < E
    int a = ei[7*2*Ee + e], b = ei[7*2*Ee + Ee + e];
    int cell = a*Nn + b;
    float x[8];
#pragma unroll
    for (int t=0;t<8;++t) x[t] = dense[t*NNc + cell];

    float A    = -expf(A_log[0]);
    float dtb  = dt_bias[0];
    float dsk  = D_skip[0];
    float wout = W_out[0];
    float win_z = swin[0], win_dt = swin[34];

    float ssm[16];
#pragma unroll
    for (int q=0;q<16;++q) ssm[q]=0.f;
    float h0=0.f,h1=0.f,h2v=0.f;
    float y=0.f;
    for (int t=0;t<8;++t){
        float xt = x[t];
        float act[33];
#pragma unroll
        for (int c=0;c<33;++c){
            float s = h0*scw[c*4+0] + h1*scw[c*4+1] + h2v*scw[c*4+2] + xt*scw[c*4+3];
            float pre = swin[1+c]*s + scb[c];
            act[c] = pre / (1.f + expf(-pre));
        }
        float x_ = act[0];
        float dtr = xt*win_dt + dtb;
        float dt  = (dtr > 20.f) ? dtr : log1pf(expf(dtr));
        float dA  = expf(dt*A);
        float dx  = dt*x_;
        float yv = 0.f;
#pragma unroll
        for (int q=0;q<16;++q){
            ssm[q] = ssm[q]*dA + dx*act[1+q];
            yv += ssm[q]*act[17+q];
        }
        yv += dsk*x_;
        float z = xt*win_z;
        yv *= z / (1.f + expf(-z));
        y = yv;
        h0=h1; h1=h2v; h2v=xt;
    }
    out[cell] = y*wout;
}

extern "C" void kernel_launch(void* const* d_in, const int* in_sizes, int n_in,
                              void* d_out, int out_size, void* d_ws, size_t ws_size,
                              hipStream_t stream)
{
    const int*   ei    = (const int*)d_in[0];
    const float* ew    = (const float*)d_in[1];
    const float* feats = (const float*)d_in[2];
    const float* noise = (const float*)d_in[3];
    const float* Wp1=(const float*)d_in[4];  const float* bp1=(const float*)d_in[5];
    const float* Wp2=(const float*)d_in[6];  const float* bp2=(const float*)d_in[7];
    const float* W1 =(const float*)d_in[8];  const float* b1 =(const float*)d_in[9];
    const float* W2 =(const float*)d_in[10]; const float* b2 =(const float*)d_in[11];
    const float* W3 =(const float*)d_in[12]; const float* b3 =(const float*)d_in[13];
    const float* w4 =(const float*)d_in[14]; const float* b4 =(const float*)d_in[15];
    const float* W_in  =(const float*)d_in[16]; const float* conv_w=(const float*)d_in[17];
    const float* conv_b=(const float*)d_in[18]; const float* dt_bias=(const float*)d_in[19];
    const float* A_log =(const float*)d_in[20]; const float* D_skip=(const float*)d_in[21];
    const float* W_out =(const float*)d_in[22];

    float* out = (float*)d_out;
    float* ws  = (float*)d_ws;
    float* emb   = ws;                      // T*N*80   = 327680
    float* hh    = emb   + 327680;          // T*N*128  = 524288
    float* agg   = hh    + 524288;          // 524288
    float* h2    = agg   + 524288;          // 524288
    float* sc    = h2    + 524288;          // T*E      = 131072
    float* dense = sc    + 131072;          // T*N*N    = 2097152
    int*   tag   = (int*)(dense + 2097152); // T*N*N ints
    float* w3t   = (float*)(tag + 2097152); // 16384

    hipMemsetAsync(agg,   0, (size_t)524288*4,  stream);
    hipMemsetAsync(dense, 0, (size_t)2097152*4, stream);
    hipMemsetAsync(tag,   0, (size_t)2097152*4, stream);
    hipMemsetAsync(out,   0, (size_t)262144*4,  stream);

    k_featproj<<<TNr/16, 256, 0, stream>>>(feats, noise, Wp1, bp1, Wp2, bp2, emb);
    k_wle1   <<<TNr/16, 256, 0, stream>>>(emb, W1, b1, hh);
    k_scatter<<<(Tt*Ee*128)/256, 256, 0, stream>>>(ei, ew, hh, agg);
    k_wle2   <<<TNr/16, 256, 0, stream>>>(hh, agg, W2, b2, h2);
    k_w3t    <<<64, 256, 0, stream>>>(W3, w3t);
    k_edge3  <<<TE/256, 256, 0, stream>>>(ei, h2, w3t, b3, w4, b4, sc);
    k_tag    <<<TE/256, 256, 0, stream>>>(ei, tag);
    k_dense  <<<TE/256, 256, 0, stream>>>(ei, sc, tag, dense);
    k_ssm    <<<Ee/256, 256, 0, stream>>>(ei, dense, W_in, conv_w, conv_b,
                                          dt_bias, A_log, D_skip, W_out, out);
}

// Round 5
// 207.890 us; speedup vs baseline: 1.7884x; 1.7884x over previous
//
#include <hip/hip_runtime.h>
#include <math.h>

#define Nn 512
#define Tt 8
#define Ee 16384
#define NNc (Nn*Nn)          // 262144
#define TNr (Tt*Nn)          // 4096
#define TE  (Tt*Ee)          // 131072

// ---------------- feat_proj: [T*N,128] -> relu -> [.,256] -> relu -> [.,64] ; concat noise -> emb[.,80]
__global__ __launch_bounds__(256) void k_featproj(
    const float* __restrict__ feats, const float* __restrict__ noise,
    const float* __restrict__ Wp1, const float* __restrict__ bp1,
    const float* __restrict__ Wp2, const float* __restrict__ bp2,
    float* __restrict__ emb)
{
    __shared__ float sfeat[16][128];
    __shared__ float sh1[16][256];
    int tid = threadIdx.x;
    int r0 = blockIdx.x * 16;
#pragma unroll
    for (int k = 0; k < 8; ++k) {
        int lin = k*256 + tid;
        sfeat[lin>>7][lin&127] = feats[(size_t)r0*128 + lin];
    }
    __syncthreads();
    {
        int j = tid;
        float acc[16];
#pragma unroll
        for (int r=0;r<16;++r) acc[r]=0.f;
        for (int i=0;i<128;i+=4) {
            float w0=Wp1[(i+0)*256+j], w1=Wp1[(i+1)*256+j];
            float w2=Wp1[(i+2)*256+j], w3=Wp1[(i+3)*256+j];
#pragma unroll
            for (int r=0;r<16;++r) {
                float4 f = *(const float4*)&sfeat[r][i];
                acc[r] += f.x*w0 + f.y*w1 + f.z*w2 + f.w*w3;
            }
        }
        float b = bp1[j];
#pragma unroll
        for (int r=0;r<16;++r) sh1[r][j] = fmaxf(acc[r]+b, 0.f);
    }
    __syncthreads();
    {
        int jo = tid & 63;
        int rr = tid >> 6;
        float b2v = bp2[jo];
        for (int rg=0; rg<4; ++rg) {
            int r = rg*4 + rr;
            float a2 = 0.f;
            for (int i=0;i<256;i+=4) {
                float4 f = *(const float4*)&sh1[r][i];
                a2 += f.x*Wp2[(i+0)*64+jo] + f.y*Wp2[(i+1)*64+jo]
                    + f.z*Wp2[(i+2)*64+jo] + f.w*Wp2[(i+3)*64+jo];
            }
            emb[(size_t)(r0+r)*80 + jo] = fmaxf(a2+b2v, 0.f);
        }
    }
    {
        int r = tid>>4, k = tid&15;
        emb[(size_t)(r0+r)*80 + 64 + k] = noise[(size_t)(r0+r)*16 + k];
    }
}

// ---------------- hh = relu(emb @ W1[80,128] + b1)
__global__ __launch_bounds__(256) void k_wle1(
    const float* __restrict__ emb, const float* __restrict__ W1,
    const float* __restrict__ b1, float* __restrict__ hh)
{
    __shared__ float semb[16][80];
    int tid = threadIdx.x;
    int r0 = blockIdx.x*16;
#pragma unroll
    for (int k=0;k<5;++k) {
        int lin = k*256+tid;
        semb[lin/80][lin%80] = emb[(size_t)r0*80 + lin];
    }
    __syncthreads();
    int j = tid & 127;
    int rb = (tid>>7)*8;
    float acc[8];
#pragma unroll
    for (int r=0;r<8;++r) acc[r]=0.f;
    for (int i=0;i<80;i+=4) {
        float w0=W1[(i+0)*128+j], w1=W1[(i+1)*128+j];
        float w2=W1[(i+2)*128+j], w3=W1[(i+3)*128+j];
#pragma unroll
        for (int r=0;r<8;++r) {
            float4 f = *(const float4*)&semb[rb+r][i];
            acc[r] += f.x*w0 + f.y*w1 + f.z*w2 + f.w*w3;
        }
    }
    float b = b1[j];
#pragma unroll
    for (int r=0;r<8;++r) hh[(size_t)(r0+rb+r)*128 + j] = fmaxf(acc[r]+b, 0.f);
}

// ---------------- msg scatter: agg[dst] += ew * hh[src]
__global__ __launch_bounds__(256) void k_scatter(
    const int* __restrict__ ei, const float* __restrict__ ew,
    const float* __restrict__ hh, float* __restrict__ agg)
{
    size_t g = (size_t)blockIdx.x*256 + threadIdx.x;   // < T*E*128
    int ch = (int)(g & 127);
    int eg = (int)(g >> 7);        // t*E+e
    int t = eg >> 14;
    int e = eg & (Ee-1);
    int dst = ei[t*2*Ee + e];
    int src = ei[t*2*Ee + Ee + e];
    float w = ew[eg];
    float v = w * hh[((size_t)(t*Nn+src))*128 + ch];
    atomicAdd(&agg[((size_t)(t*Nn+dst))*128 + ch], v);
}

// ---------------- h2 = relu((hh+agg) @ W2[128,128] + b2)
__global__ __launch_bounds__(256) void k_wle2(
    const float* __restrict__ hh, const float* __restrict__ agg,
    const float* __restrict__ W2, const float* __restrict__ b2,
    float* __restrict__ h2)
{
    __shared__ float sx[16][128];
    int tid=threadIdx.x; int r0=blockIdx.x*16;
#pragma unroll
    for (int k=0;k<8;++k){
        int lin=k*256+tid;
        size_t gidx=(size_t)r0*128+lin;
        sx[lin>>7][lin&127]=hh[gidx]+agg[gidx];
    }
    __syncthreads();
    int j=tid&127; int rb=(tid>>7)*8;
    float acc[8];
#pragma unroll
    for(int r=0;r<8;++r)acc[r]=0.f;
    for(int i=0;i<128;i+=4){
        float w0=W2[(i+0)*128+j], w1=W2[(i+1)*128+j];
        float w2v=W2[(i+2)*128+j], w3=W2[(i+3)*128+j];
#pragma unroll
        for(int r=0;r<8;++r){
            float4 f=*(const float4*)&sx[rb+r][i];
            acc[r]+=f.x*w0+f.y*w1+f.z*w2v+f.w*w3;
        }
    }
    float b=b2[j];
#pragma unroll
    for(int r=0;r<8;++r) h2[(size_t)(r0+rb+r)*128+j]=fmaxf(acc[r]+b,0.f);
}

// ---------------- edge scores as register-tiled GEMM:
// C[128e x 128j] per block; threads 16(tx:j) x 16(ty:e); 8x8 acc tile/thread.
// sEf[e][k] pad-33 (conflict-free b32 broadcast reads), sW k-chunked.
#define KC 32
__global__ __launch_bounds__(256) void k_edge4(
    const int* __restrict__ ei, const float* __restrict__ h2,
    const float* __restrict__ W3, const float* __restrict__ b3,
    const float* __restrict__ w4, const float* __restrict__ b4,
    float* __restrict__ sc)
{
    __shared__ float sEf[128*33];     // 16896 B
    __shared__ float sW[KC*128];      // 16384 B
    int tid = threadIdx.x;
    int bid = blockIdx.x;
    int tb  = bid >> 7;               // timestep (128 blocks per t)
    int e_loc = tid & 127;            // staging: edge within block
    int hHalf = tid >> 7;             // staging: k-half (0/1)
    int ein = (bid & 127)*128 + e_loc;
    int a = ei[tb*2*Ee + ein];
    int b = ei[tb*2*Ee + Ee + ein];
    const float4* __restrict__ pa = (const float4*)&h2[((size_t)(tb*Nn+a))*128];
    const float4* __restrict__ pb = (const float4*)&h2[((size_t)(tb*Nn+b))*128];

    int tx = tid & 15, ty = tid >> 4;
    int j0 = tx*8, e0 = ty*8;
    float4 b3lo = *(const float4*)&b3[j0];
    float4 b3hi = *(const float4*)&b3[j0+4];
    float4 w4lo = *(const float4*)&w4[j0];
    float4 w4hi = *(const float4*)&w4[j0+4];

    float acc[8][8];
#pragma unroll
    for (int i=0;i<8;++i)
#pragma unroll
        for (int j=0;j<8;++j) acc[i][j]=0.f;

    for (int c=0;c<4;++c){
        int k0 = c*KC;
        __syncthreads();
        // stage W chunk [KC][128] (linear copy, coalesced)
        {
            const float4* __restrict__ src = (const float4*)&W3[k0*128];
            float4* dst = (float4*)sW;
#pragma unroll
            for (int q=0;q<4;++q) dst[q*256+tid] = src[q*256+tid];
        }
        // stage ef chunk: this thread covers 16 k's of its edge
        {
            int kk = hHalf*16;
            int kg = (k0 + kk) >> 2;
            float* __restrict__ d = &sEf[e_loc*33 + kk];
#pragma unroll
            for (int q=0;q<4;++q){
                float4 x = pa[kg+q], y = pb[kg+q];
                d[q*4+0]=x.x*y.x; d[q*4+1]=x.y*y.y; d[q*4+2]=x.z*y.z; d[q*4+3]=x.w*y.w;
            }
        }
        __syncthreads();
#pragma unroll 8
        for (int kk=0;kk<KC;++kk){
            float af[8];
#pragma unroll
            for (int i=0;i<8;++i) af[i] = sEf[(e0+i)*33 + kk];
            float4 b0 = *(const float4*)&sW[kk*128 + j0];
            float4 b1 = *(const float4*)&sW[kk*128 + j0 + 4];
#pragma unroll
            for (int i=0;i<8;++i){
                acc[i][0] += af[i]*b0.x;
                acc[i][1] += af[i]*b0.y;
                acc[i][2] += af[i]*b0.z;
                acc[i][3] += af[i]*b0.w;
                acc[i][4] += af[i]*b1.x;
                acc[i][5] += af[i]*b1.y;
                acc[i][6] += af[i]*b1.z;
                acc[i][7] += af[i]*b1.w;
            }
        }
    }
    // epilogue: p_e = sum_j relu(acc+b3)*w4, reduce across 16 tx lanes
    float b4v = b4[0];
#pragma unroll
    for (int i=0;i<8;++i){
        float p = fmaxf(acc[i][0]+b3lo.x,0.f)*w4lo.x
                + fmaxf(acc[i][1]+b3lo.y,0.f)*w4lo.y
                + fmaxf(acc[i][2]+b3lo.z,0.f)*w4lo.z
                + fmaxf(acc[i][3]+b3lo.w,0.f)*w4lo.w
                + fmaxf(acc[i][4]+b3hi.x,0.f)*w4hi.x
                + fmaxf(acc[i][5]+b3hi.y,0.f)*w4hi.y
                + fmaxf(acc[i][6]+b3hi.z,0.f)*w4hi.z
                + fmaxf(acc[i][7]+b3hi.w,0.f)*w4hi.w;
        p += __shfl_xor(p,1);
        p += __shfl_xor(p,2);
        p += __shfl_xor(p,4);
        p += __shfl_xor(p,8);
        if (tx==0) sc[bid*128 + e0 + i] = p + b4v;
    }
}

// ---------------- densify with last-write-wins: tag pass then write pass
__global__ __launch_bounds__(256) void k_tag(const int* __restrict__ ei, int* __restrict__ tag)
{
    int g = blockIdx.x*256+threadIdx.x;        // < T*E
    int t = g>>14, e = g&(Ee-1);
    int a = ei[t*2*Ee + e], b = ei[t*2*Ee + Ee + e];
    atomicMax(&tag[t*NNc + a*Nn + b], g+1);
}

__global__ __launch_bounds__(256) void k_dense(
    const int* __restrict__ ei, const float* __restrict__ sc,
    const int* __restrict__ tag, float* __restrict__ dense)
{
    int g = blockIdx.x*256+threadIdx.x;
    int t = g>>14, e = g&(Ee-1);
    int a = ei[t*2*Ee + e], b = ei[t*2*Ee + Ee + e];
    int cell = t*NNc + a*Nn + b;
    if (tag[cell] == g+1) dense[cell] = sc[g];
}

// ---------------- SSM recurrence: only cells with an edge at t=T-1 have nonzero output
__global__ __launch_bounds__(256) void k_ssm(
    const int* __restrict__ ei, const float* __restrict__ dense,
    const float* __restrict__ W_in, const float* __restrict__ conv_w,
    const float* __restrict__ conv_b, const float* __restrict__ dt_bias,
    const float* __restrict__ A_log, const float* __restrict__ D_skip,
    const float* __restrict__ W_out, float* __restrict__ out)
{
    __shared__ float scw[132], scb[33], swin[35];
    int tid = threadIdx.x;
    if (tid < 132) scw[tid] = conv_w[tid];
    if (tid < 33)  scb[tid] = conv_b[tid];
    if (tid < 35)  swin[tid] = W_in[tid];
    __syncthreads();

    int e = blockIdx.x*256 + tid;              // < E
    int a = ei[7*2*Ee + e], b = ei[7*2*Ee + Ee + e];
    int cell = a*Nn + b;
    float x[8];
#pragma unroll
    for (int t=0;t<8;++t) x[t] = dense[t*NNc + cell];

    float A    = -expf(A_log[0]);
    float dtb  = dt_bias[0];
    float dsk  = D_skip[0];
    float wout = W_out[0];
    float win_z = swin[0], win_dt = swin[34];

    float ssm[16];
#pragma unroll
    for (int q=0;q<16;++q) ssm[q]=0.f;
    float h0=0.f,h1=0.f,h2v=0.f;
    float y=0.f;
    for (int t=0;t<8;++t){
        float xt = x[t];
        float act[33];
#pragma unroll
        for (int c=0;c<33;++c){
            float s = h0*scw[c*4+0] + h1*scw[c*4+1] + h2v*scw[c*4+2] + xt*scw[c*4+3];
            float pre = swin[1+c]*s + scb[c];
            act[c] = pre / (1.f + expf(-pre));
        }
        float x_ = act[0];
        float dtr = xt*win_dt + dtb;
        float dt  = (dtr > 20.f) ? dtr : log1pf(expf(dtr));
        float dA  = expf(dt*A);
        float dx  = dt*x_;
        float yv = 0.f;
#pragma unroll
        for (int q=0;q<16;++q){
            ssm[q] = ssm[q]*dA + dx*act[1+q];
            yv += ssm[q]*act[17+q];
        }
        yv += dsk*x_;
        float z = xt*win_z;
        yv *= z / (1.f + expf(-z));
        y = yv;
        h0=h1; h1=h2v; h2v=xt;
    }
    out[cell] = y*wout;
}

extern "C" void kernel_launch(void* const* d_in, const int* in_sizes, int n_in,
                              void* d_out, int out_size, void* d_ws, size_t ws_size,
                              hipStream_t stream)
{
    const int*   ei    = (const int*)d_in[0];
    const float* ew    = (const float*)d_in[1];
    const float* feats = (const float*)d_in[2];
    const float* noise = (const float*)d_in[3];
    const float* Wp1=(const float*)d_in[4];  const float* bp1=(const float*)d_in[5];
    const float* Wp2=(const float*)d_in[6];  const float* bp2=(const float*)d_in[7];
    const float* W1 =(const float*)d_in[8];  const float* b1 =(const float*)d_in[9];
    const float* W2 =(const float*)d_in[10]; const float* b2 =(const float*)d_in[11];
    const float* W3 =(const float*)d_in[12]; const float* b3 =(const float*)d_in[13];
    const float* w4 =(const float*)d_in[14]; const float* b4 =(const float*)d_in[15];
    const float* W_in  =(const float*)d_in[16]; const float* conv_w=(const float*)d_in[17];
    const float* conv_b=(const float*)d_in[18]; const float* dt_bias=(const float*)d_in[19];
    const float* A_log =(const float*)d_in[20]; const float* D_skip=(const float*)d_in[21];
    const float* W_out =(const float*)d_in[22];

    float* out = (float*)d_out;
    float* ws  = (float*)d_ws;
    float* emb   = ws;                      // T*N*80   = 327680
    float* hh    = emb   + 327680;          // T*N*128  = 524288
    float* agg   = hh    + 524288;          // 524288
    float* h2    = agg   + 524288;          // 524288
    float* sc    = h2    + 524288;          // T*E      = 131072
    float* dense = sc    + 131072;          // T*N*N    = 2097152
    int*   tag   = (int*)(dense + 2097152); // T*N*N ints

    hipMemsetAsync(agg,   0, (size_t)524288*4,  stream);
    hipMemsetAsync(dense, 0, (size_t)2097152*4, stream);
    hipMemsetAsync(tag,   0, (size_t)2097152*4, stream);
    hipMemsetAsync(out,   0, (size_t)262144*4,  stream);

    k_featproj<<<TNr/16, 256, 0, stream>>>(feats, noise, Wp1, bp1, Wp2, bp2, emb);
    k_wle1   <<<TNr/16, 256, 0, stream>>>(emb, W1, b1, hh);
    k_scatter<<<(Tt*Ee*128)/256, 256, 0, stream>>>(ei, ew, hh, agg);
    k_wle2   <<<TNr/16, 256, 0, stream>>>(hh, agg, W2, b2, h2);
    k_edge4  <<<TE/128, 256, 0, stream>>>(ei, h2, W3, b3, w4, b4, sc);
    k_tag    <<<TE/256, 256, 0, stream>>>(ei, tag);
    k_dense  <<<TE/256, 256, 0, stream>>>(ei, sc, tag, dense);
    k_ssm    <<<Ee/256, 256, 0, stream>>>(ei, dense, W_in, conv_w, conv_b,
                                          dt_bias, A_log, D_skip, W_out, out);
}

// Round 6
// 174.609 us; speedup vs baseline: 2.1292x; 1.1906x over previous
//
#include <hip/hip_runtime.h>
#include <math.h>

#define Nn 512
#define Tt 8
#define Ee 16384
#define NNc (Nn*Nn)          // 262144
#define TNr (Tt*Nn)          // 4096
#define TE  (Tt*Ee)          // 131072
#define CAP 128              // bucket capacity per (t,dst); Poisson(32) => overflow ~1e-35

// ---------------- feat_proj: [T*N,128] -> relu -> [.,256] -> relu -> [.,64] ; concat noise -> emb[.,80]
__global__ __launch_bounds__(256) void k_featproj(
    const float* __restrict__ feats, const float* __restrict__ noise,
    const float* __restrict__ Wp1, const float* __restrict__ bp1,
    const float* __restrict__ Wp2, const float* __restrict__ bp2,
    float* __restrict__ emb)
{
    __shared__ float sfeat[16][128];
    __shared__ float sh1[16][256];
    int tid = threadIdx.x;
    int r0 = blockIdx.x * 16;
#pragma unroll
    for (int k = 0; k < 8; ++k) {
        int lin = k*256 + tid;
        sfeat[lin>>7][lin&127] = feats[(size_t)r0*128 + lin];
    }
    __syncthreads();
    {
        int j = tid;
        float acc[16];
#pragma unroll
        for (int r=0;r<16;++r) acc[r]=0.f;
        for (int i=0;i<128;i+=4) {
            float w0=Wp1[(i+0)*256+j], w1=Wp1[(i+1)*256+j];
            float w2=Wp1[(i+2)*256+j], w3=Wp1[(i+3)*256+j];
#pragma unroll
            for (int r=0;r<16;++r) {
                float4 f = *(const float4*)&sfeat[r][i];
                acc[r] += f.x*w0 + f.y*w1 + f.z*w2 + f.w*w3;
            }
        }
        float b = bp1[j];
#pragma unroll
        for (int r=0;r<16;++r) sh1[r][j] = fmaxf(acc[r]+b, 0.f);
    }
    __syncthreads();
    {
        int jo = tid & 63;
        int rr = tid >> 6;
        float b2v = bp2[jo];
        for (int rg=0; rg<4; ++rg) {
            int r = rg*4 + rr;
            float a2 = 0.f;
            for (int i=0;i<256;i+=4) {
                float4 f = *(const float4*)&sh1[r][i];
                a2 += f.x*Wp2[(i+0)*64+jo] + f.y*Wp2[(i+1)*64+jo]
                    + f.z*Wp2[(i+2)*64+jo] + f.w*Wp2[(i+3)*64+jo];
            }
            emb[(size_t)(r0+r)*80 + jo] = fmaxf(a2+b2v, 0.f);
        }
    }
    {
        int r = tid>>4, k = tid&15;
        emb[(size_t)(r0+r)*80 + 64 + k] = noise[(size_t)(r0+r)*16 + k];
    }
}

// ---------------- hh = relu(emb @ W1[80,128] + b1)
__global__ __launch_bounds__(256) void k_wle1(
    const float* __restrict__ emb, const float* __restrict__ W1,
    const float* __restrict__ b1, float* __restrict__ hh)
{
    __shared__ float semb[16][80];
    int tid = threadIdx.x;
    int r0 = blockIdx.x*16;
#pragma unroll
    for (int k=0;k<5;++k) {
        int lin = k*256+tid;
        semb[lin/80][lin%80] = emb[(size_t)r0*80 + lin];
    }
    __syncthreads();
    int j = tid & 127;
    int rb = (tid>>7)*8;
    float acc[8];
#pragma unroll
    for (int r=0;r<8;++r) acc[r]=0.f;
    for (int i=0;i<80;i+=4) {
        float w0=W1[(i+0)*128+j], w1=W1[(i+1)*128+j];
        float w2=W1[(i+2)*128+j], w3=W1[(i+3)*128+j];
#pragma unroll
        for (int r=0;r<8;++r) {
            float4 f = *(const float4*)&semb[rb+r][i];
            acc[r] += f.x*w0 + f.y*w1 + f.z*w2 + f.w*w3;
        }
    }
    float b = b1[j];
#pragma unroll
    for (int r=0;r<8;++r) hh[(size_t)(r0+rb+r)*128 + j] = fmaxf(acc[r]+b, 0.f);
}

// ---------------- bucket-CSR build: slot = atomicAdd(cnt[t*N+dst]); bucket[..slot] = e
__global__ __launch_bounds__(256) void k_hist(
    const int* __restrict__ ei, int* __restrict__ cnt, int* __restrict__ bucket)
{
    int g = blockIdx.x*256 + threadIdx.x;       // < T*E
    int t = g>>14, e = g&(Ee-1);
    int dst = ei[t*2*Ee + e];
    int cell = t*Nn + dst;
    int pos = atomicAdd(&cnt[cell], 1);
    if (pos < CAP) bucket[cell*CAP + pos] = e;
}

// ---------------- agg[t,dst,:] = sum_{e in bucket} ew[e] * hh[t,src(e),:]  (no atomics)
__global__ __launch_bounds__(128) void k_scatter2(
    const int* __restrict__ ei, const float* __restrict__ ew,
    const float* __restrict__ hh, const int* __restrict__ cnt,
    const int* __restrict__ bucket, float* __restrict__ agg)
{
    int bid = blockIdx.x;            // < T*Nn
    int t = bid >> 9;
    int ch = threadIdx.x;
    int n = cnt[bid]; n = n < CAP ? n : CAP;
    const int* __restrict__ bk = &bucket[(size_t)bid*CAP];
    const int* __restrict__ eis = &ei[t*2*Ee + Ee];
    const float* __restrict__ ewt = &ew[t*Ee];
    const float* __restrict__ hht = &hh[(size_t)t*Nn*128];
    float acc = 0.f;
    int i = 0;
    for (; i+1 < n; i += 2){
        int e0 = bk[i], e1 = bk[i+1];
        int s0 = eis[e0], s1 = eis[e1];
        float w0 = ewt[e0], w1 = ewt[e1];
        acc += w0*hht[(size_t)s0*128 + ch] + w1*hht[(size_t)s1*128 + ch];
    }
    if (i < n){
        int e0 = bk[i];
        acc += ewt[e0]*hht[(size_t)eis[e0]*128 + ch];
    }
    agg[(size_t)bid*128 + ch] = acc;
}

// ---------------- h2 = relu((hh+agg) @ W2[128,128] + b2)
__global__ __launch_bounds__(256) void k_wle2(
    const float* __restrict__ hh, const float* __restrict__ agg,
    const float* __restrict__ W2, const float* __restrict__ b2,
    float* __restrict__ h2)
{
    __shared__ float sx[16][128];
    int tid=threadIdx.x; int r0=blockIdx.x*16;
#pragma unroll
    for (int k=0;k<8;++k){
        int lin=k*256+tid;
        size_t gidx=(size_t)r0*128+lin;
        sx[lin>>7][lin&127]=hh[gidx]+agg[gidx];
    }
    __syncthreads();
    int j=tid&127; int rb=(tid>>7)*8;
    float acc[8];
#pragma unroll
    for(int r=0;r<8;++r)acc[r]=0.f;
    for(int i=0;i<128;i+=4){
        float w0=W2[(i+0)*128+j], w1=W2[(i+1)*128+j];
        float w2v=W2[(i+2)*128+j], w3=W2[(i+3)*128+j];
#pragma unroll
        for(int r=0;r<8;++r){
            float4 f=*(const float4*)&sx[rb+r][i];
            acc[r]+=f.x*w0+f.y*w1+f.z*w2v+f.w*w3;
        }
    }
    float b=b2[j];
#pragma unroll
    for(int r=0;r<8;++r) h2[(size_t)(r0+rb+r)*128+j]=fmaxf(acc[r]+b,0.f);
}

// ---------------- edge scores as register-tiled GEMM (conflict-free LDS):
// sE[k][e] (stride 136) -> ef reads are 2x b128 broadcast; sW j-split tx*4 / 64+tx*4
// -> W reads are 2x b128 covering all 32 banks 2-way (free).
#define KC 32
__global__ __launch_bounds__(256) void k_edge5(
    const int* __restrict__ ei, const float* __restrict__ h2,
    const float* __restrict__ W3, const float* __restrict__ b3,
    const float* __restrict__ w4, const float* __restrict__ b4,
    float* __restrict__ sc)
{
    __shared__ float sE[KC*136];      // 17408 B
    __shared__ float sW[KC*128];      // 16384 B
    int tid = threadIdx.x;
    int bid = blockIdx.x;
    int tb  = bid >> 7;               // timestep (128 blocks per t)
    int e_loc = tid & 127;            // staging: edge within block
    int hHalf = tid >> 7;             // staging: k-half (0/1)
    int ein = (bid & 127)*128 + e_loc;
    int a = ei[tb*2*Ee + ein];
    int b = ei[tb*2*Ee + Ee + ein];
    const float4* __restrict__ pa = (const float4*)&h2[((size_t)(tb*Nn+a))*128];
    const float4* __restrict__ pb = (const float4*)&h2[((size_t)(tb*Nn+b))*128];

    int tx = tid & 15, ty = tid >> 4;
    int e0 = ty*8;
    int jA = tx*4, jB = 64 + tx*4;
    float4 b3A = *(const float4*)&b3[jA];
    float4 b3B = *(const float4*)&b3[jB];
    float4 w4A = *(const float4*)&w4[jA];
    float4 w4B = *(const float4*)&w4[jB];

    float acc[8][8];
#pragma unroll
    for (int i=0;i<8;++i)
#pragma unroll
        for (int j=0;j<8;++j) acc[i][j]=0.f;

    for (int c=0;c<4;++c){
        int k0 = c*KC;
        __syncthreads();
        // stage W chunk [KC][128] (linear copy, coalesced)
        {
            const float4* __restrict__ src = (const float4*)&W3[k0*128];
            float4* dst = (float4*)sW;
#pragma unroll
            for (int q=0;q<4;++q) dst[q*256+tid] = src[q*256+tid];
        }
        // stage ef chunk TRANSPOSED: sE[k][e], this thread covers 16 k's of its edge
        {
            int kb = hHalf*16;
            int kg = (k0 + kb) >> 2;
#pragma unroll
            for (int q=0;q<4;++q){
                float4 x = pa[kg+q], y = pb[kg+q];
                sE[(kb+q*4+0)*136 + e_loc] = x.x*y.x;
                sE[(kb+q*4+1)*136 + e_loc] = x.y*y.y;
                sE[(kb+q*4+2)*136 + e_loc] = x.z*y.z;
                sE[(kb+q*4+3)*136 + e_loc] = x.w*y.w;
            }
        }
        __syncthreads();
#pragma unroll
        for (int kk=0;kk<KC;++kk){
            float4 ea = *(const float4*)&sE[kk*136 + e0];
            float4 eb = *(const float4*)&sE[kk*136 + e0 + 4];
            float4 wA = *(const float4*)&sW[kk*128 + jA];
            float4 wB = *(const float4*)&sW[kk*128 + jB];
            float ev0=ea.x, ev1=ea.y, ev2=ea.z, ev3=ea.w;
            float ev4=eb.x, ev5=eb.y, ev6=eb.z, ev7=eb.w;
#define ROW(i, ev) \
            acc[i][0]+=ev*wA.x; acc[i][1]+=ev*wA.y; acc[i][2]+=ev*wA.z; acc[i][3]+=ev*wA.w; \
            acc[i][4]+=ev*wB.x; acc[i][5]+=ev*wB.y; acc[i][6]+=ev*wB.z; acc[i][7]+=ev*wB.w;
            ROW(0,ev0) ROW(1,ev1) ROW(2,ev2) ROW(3,ev3)
            ROW(4,ev4) ROW(5,ev5) ROW(6,ev6) ROW(7,ev7)
#undef ROW
        }
    }
    // epilogue: p_e = sum_j relu(acc+b3)*w4, reduce across 16 tx lanes
    float b4v = b4[0];
#pragma unroll
    for (int i=0;i<8;++i){
        float p = fmaxf(acc[i][0]+b3A.x,0.f)*w4A.x
                + fmaxf(acc[i][1]+b3A.y,0.f)*w4A.y
                + fmaxf(acc[i][2]+b3A.z,0.f)*w4A.z
                + fmaxf(acc[i][3]+b3A.w,0.f)*w4A.w
                + fmaxf(acc[i][4]+b3B.x,0.f)*w4B.x
                + fmaxf(acc[i][5]+b3B.y,0.f)*w4B.y
                + fmaxf(acc[i][6]+b3B.z,0.f)*w4B.z
                + fmaxf(acc[i][7]+b3B.w,0.f)*w4B.w;
        p += __shfl_xor(p,1);
        p += __shfl_xor(p,2);
        p += __shfl_xor(p,4);
        p += __shfl_xor(p,8);
        if (tx==0) sc[bid*128 + e0 + i] = p + b4v;
    }
}

// ---------------- densify with last-write-wins: tag pass then write pass
__global__ __launch_bounds__(256) void k_tag(const int* __restrict__ ei, int* __restrict__ tag)
{
    int g = blockIdx.x*256+threadIdx.x;        // < T*E
    int t = g>>14, e = g&(Ee-1);
    int a = ei[t*2*Ee + e], b = ei[t*2*Ee + Ee + e];
    atomicMax(&tag[t*NNc + a*Nn + b], g+1);
}

__global__ __launch_bounds__(256) void k_dense(
    const int* __restrict__ ei, const float* __restrict__ sc,
    const int* __restrict__ tag, float* __restrict__ dense)
{
    int g = blockIdx.x*256+threadIdx.x;
    int t = g>>14, e = g&(Ee-1);
    int a = ei[t*2*Ee + e], b = ei[t*2*Ee + Ee + e];
    int cell = t*NNc + a*Nn + b;
    if (tag[cell] == g+1) dense[cell] = sc[g];
}

// ---------------- SSM recurrence: only cells with an edge at t=T-1 have nonzero output
__global__ __launch_bounds__(256) void k_ssm(
    const int* __restrict__ ei, const float* __restrict__ dense,
    const float* __restrict__ W_in, const float* __restrict__ conv_w,
    const float* __restrict__ conv_b, const float* __restrict__ dt_bias,
    const float* __restrict__ A_log, const float* __restrict__ D_skip,
    const float* __restrict__ W_out, float* __restrict__ out)
{
    __shared__ float scw[132], scb[33], swin[35];
    int tid = threadIdx.x;
    if (tid < 132) scw[tid] = conv_w[tid];
    if (tid < 33)  scb[tid] = conv_b[tid];
    if (tid < 35)  swin[tid] = W_in[tid];
    __syncthreads();

    int e = blockIdx.x*256 + tid;              // < E
    int a = ei[7*2*Ee + e], b = ei[7*2*Ee + Ee + e];
    int cell = a*Nn + b;
    float x[8];
#pragma unroll
    for (int t=0;t<8;++t) x[t] = dense[t*NNc + cell];

    float A    = -expf(A_log[0]);
    float dtb  = dt_bias[0];
    float dsk  = D_skip[0];
    float wout = W_out[0];
    float win_z = swin[0], win_dt = swin[34];

    float ssm[16];
#pragma unroll
    for (int q=0;q<16;++q) ssm[q]=0.f;
    float h0=0.f,h1=0.f,h2v=0.f;
    float y=0.f;
    for (int t=0;t<8;++t){
        float xt = x[t];
        float act[33];
#pragma unroll
        for (int c=0;c<33;++c){
            float s = h0*scw[c*4+0] + h1*scw[c*4+1] + h2v*scw[c*4+2] + xt*scw[c*4+3];
            float pre = swin[1+c]*s + scb[c];
            act[c] = pre / (1.f + expf(-pre));
        }
        float x_ = act[0];
        float dtr = xt*win_dt + dtb;
        float dt  = (dtr > 20.f) ? dtr : log1pf(expf(dtr));
        float dA  = expf(dt*A);
        float dx  = dt*x_;
        float yv = 0.f;
#pragma unroll
        for (int q=0;q<16;++q){
            ssm[q] = ssm[q]*dA + dx*act[1+q];
            yv += ssm[q]*act[17+q];
        }
        yv += dsk*x_;
        float z = xt*win_z;
        yv *= z / (1.f + expf(-z));
        y = yv;
        h0=h1; h1=h2v; h2v=xt;
    }
    out[cell] = y*wout;
}

extern "C" void kernel_launch(void* const* d_in, const int* in_sizes, int n_in,
                              void* d_out, int out_size, void* d_ws, size_t ws_size,
                              hipStream_t stream)
{
    const int*   ei    = (const int*)d_in[0];
    const float* ew    = (const float*)d_in[1];
    const float* feats = (const float*)d_in[2];
    const float* noise = (const float*)d_in[3];
    const float* Wp1=(const float*)d_in[4];  const float* bp1=(const float*)d_in[5];
    const float* Wp2=(const float*)d_in[6];  const float* bp2=(const float*)d_in[7];
    const float* W1 =(const float*)d_in[8];  const float* b1 =(const float*)d_in[9];
    const float* W2 =(const float*)d_in[10]; const float* b2 =(const float*)d_in[11];
    const float* W3 =(const float*)d_in[12]; const float* b3 =(const float*)d_in[13];
    const float* w4 =(const float*)d_in[14]; const float* b4 =(const float*)d_in[15];
    const float* W_in  =(const float*)d_in[16]; const float* conv_w=(const float*)d_in[17];
    const float* conv_b=(const float*)d_in[18]; const float* dt_bias=(const float*)d_in[19];
    const float* A_log =(const float*)d_in[20]; const float* D_skip=(const float*)d_in[21];
    const float* W_out =(const float*)d_in[22];

    float* out = (float*)d_out;
    float* ws  = (float*)d_ws;
    float* emb   = ws;                      // T*N*80   = 327680
    float* hh    = emb   + 327680;          // T*N*128  = 524288
    float* agg   = hh    + 524288;          // 524288
    float* h2    = agg   + 524288;          // 524288
    float* sc    = h2    + 524288;          // T*E      = 131072
    float* dense = sc    + 131072;          // T*N*N    = 2097152
    int*   tag   = (int*)(dense + 2097152); // T*N*N ints
    // cnt/bucket OVERLAY the dense region (consumed before dense memset)
    int*   cnt    = (int*)dense;            // T*N = 4096 ints
    int*   bucket = cnt + TNr;              // T*N*CAP = 524288 ints

    hipMemsetAsync(out, 0, (size_t)262144*4, stream);
    hipMemsetAsync(cnt, 0, (size_t)TNr*4,    stream);

    k_hist    <<<TE/256, 256, 0, stream>>>(ei, cnt, bucket);
    k_featproj<<<TNr/16, 256, 0, stream>>>(feats, noise, Wp1, bp1, Wp2, bp2, emb);
    k_wle1    <<<TNr/16, 256, 0, stream>>>(emb, W1, b1, hh);
    k_scatter2<<<TNr, 128, 0, stream>>>(ei, ew, hh, cnt, bucket, agg);
    k_wle2    <<<TNr/16, 256, 0, stream>>>(hh, agg, W2, b2, h2);
    k_edge5   <<<TE/128, 256, 0, stream>>>(ei, h2, W3, b3, w4, b4, sc);

    // bucket/cnt dead from here; reuse region as dense
    hipMemsetAsync(dense, 0, (size_t)2097152*4, stream);
    hipMemsetAsync(tag,   0, (size_t)2097152*4, stream);

    k_tag   <<<TE/256, 256, 0, stream>>>(ei, tag);
    k_dense <<<TE/256, 256, 0, stream>>>(ei, sc, tag, dense);
    k_ssm   <<<Ee/256, 256, 0, stream>>>(ei, dense, W_in, conv_w, conv_b,
                                         dt_bias, A_log, D_skip, W_out, out);
}

// Round 7
// 168.209 us; speedup vs baseline: 2.2103x; 1.0380x over previous
//
#include <hip/hip_runtime.h>
#include <math.h>

#define Nn 512
#define Tt 8
#define Ee 16384
#define NNc (Nn*Nn)          // 262144
#define TNr (Tt*Nn)          // 4096
#define TE  (Tt*Ee)          // 131072
#define CAP 128              // bucket capacity per (t,dst); Poisson(32) => overflow ~1e-35

// ---------------- fused feat_proj + WLE layer1:
// feats[16 rows,128] -> relu(256) -> relu(64) ; concat noise -> emb(LDS) -> hh = relu(emb@W1+b1)
__global__ __launch_bounds__(256) void k_fp1(
    const float* __restrict__ feats, const float* __restrict__ noise,
    const float* __restrict__ Wp1, const float* __restrict__ bp1,
    const float* __restrict__ Wp2, const float* __restrict__ bp2,
    const float* __restrict__ W1, const float* __restrict__ b1,
    float* __restrict__ hh)
{
    __shared__ float sfeat[16][128];
    __shared__ float sh1[16][256];
    __shared__ float semb[16][80];
    int tid = threadIdx.x;
    int r0 = blockIdx.x * 16;
#pragma unroll
    for (int k = 0; k < 8; ++k) {
        int lin = k*256 + tid;
        sfeat[lin>>7][lin&127] = feats[(size_t)r0*128 + lin];
    }
    // noise -> semb[:, 64:80]
    {
        int r = tid>>4, k = tid&15;
        semb[r][64+k] = noise[(size_t)(r0+r)*16 + k];
    }
    __syncthreads();
    // h1: 256 outputs, one per thread, 16 rows each
    {
        int j = tid;
        float acc[16];
#pragma unroll
        for (int r=0;r<16;++r) acc[r]=0.f;
        for (int i=0;i<128;i+=4) {
            float w0=Wp1[(i+0)*256+j], w1=Wp1[(i+1)*256+j];
            float w2=Wp1[(i+2)*256+j], w3=Wp1[(i+3)*256+j];
#pragma unroll
            for (int r=0;r<16;++r) {
                float4 f = *(const float4*)&sfeat[r][i];
                acc[r] += f.x*w0 + f.y*w1 + f.z*w2 + f.w*w3;
            }
        }
        float b = bp1[j];
#pragma unroll
        for (int r=0;r<16;++r) sh1[r][j] = fmaxf(acc[r]+b, 0.f);
    }
    __syncthreads();
    // h2 -> semb[:, 0:64]
    {
        int jo = tid & 63;
        int rr = tid >> 6;
        float b2v = bp2[jo];
        for (int rg=0; rg<4; ++rg) {
            int r = rg*4 + rr;
            float a2 = 0.f;
            for (int i=0;i<256;i+=4) {
                float4 f = *(const float4*)&sh1[r][i];
                a2 += f.x*Wp2[(i+0)*64+jo] + f.y*Wp2[(i+1)*64+jo]
                    + f.z*Wp2[(i+2)*64+jo] + f.w*Wp2[(i+3)*64+jo];
            }
            semb[r][jo] = fmaxf(a2+b2v, 0.f);
        }
    }
    __syncthreads();
    // hh = relu(semb @ W1[80,128] + b1)
    {
        int j = tid & 127;
        int rb = (tid>>7)*8;
        float acc[8];
#pragma unroll
        for (int r=0;r<8;++r) acc[r]=0.f;
        for (int i=0;i<80;i+=4) {
            float w0=W1[(i+0)*128+j], w1=W1[(i+1)*128+j];
            float w2=W1[(i+2)*128+j], w3=W1[(i+3)*128+j];
#pragma unroll
            for (int r=0;r<8;++r) {
                float4 f = *(const float4*)&semb[rb+r][i];
                acc[r] += f.x*w0 + f.y*w1 + f.z*w2 + f.w*w3;
            }
        }
        float b = b1[j];
#pragma unroll
        for (int r=0;r<8;++r) hh[(size_t)(r0+rb+r)*128 + j] = fmaxf(acc[r]+b, 0.f);
    }
}

// ---------------- bucket-CSR build: slot = atomicAdd(cnt[t*N+dst]); bucket[..slot] = e
__global__ __launch_bounds__(256) void k_hist(
    const int* __restrict__ ei, int* __restrict__ cnt, int* __restrict__ bucket)
{
    int g = blockIdx.x*256 + threadIdx.x;       // < T*E
    int t = g>>14, e = g&(Ee-1);
    int dst = ei[t*2*Ee + e];
    int cell = t*Nn + dst;
    int pos = atomicAdd(&cnt[cell], 1);
    if (pos < CAP) bucket[cell*CAP + pos] = e;
}

// ---------------- agg[t,dst,:] = sum_{e in bucket} ew[e] * hh[t,src(e),:]  (no atomics)
__global__ __launch_bounds__(128) void k_scatter2(
    const int* __restrict__ ei, const float* __restrict__ ew,
    const float* __restrict__ hh, const int* __restrict__ cnt,
    const int* __restrict__ bucket, float* __restrict__ agg)
{
    int bid = blockIdx.x;            // < T*Nn
    int t = bid >> 9;
    int ch = threadIdx.x;
    int n = cnt[bid]; n = n < CAP ? n : CAP;
    const int* __restrict__ bk = &bucket[(size_t)bid*CAP];
    const int* __restrict__ eis = &ei[t*2*Ee + Ee];
    const float* __restrict__ ewt = &ew[t*Ee];
    const float* __restrict__ hht = &hh[(size_t)t*Nn*128];
    float acc = 0.f;
    int i = 0;
    for (; i+1 < n; i += 2){
        int e0 = bk[i], e1 = bk[i+1];
        int s0 = eis[e0], s1 = eis[e1];
        float w0 = ewt[e0], w1 = ewt[e1];
        acc += w0*hht[(size_t)s0*128 + ch] + w1*hht[(size_t)s1*128 + ch];
    }
    if (i < n){
        int e0 = bk[i];
        acc += ewt[e0]*hht[(size_t)eis[e0]*128 + ch];
    }
    agg[(size_t)bid*128 + ch] = acc;
}

// ---------------- h2 = relu((hh+agg) @ W2[128,128] + b2)
__global__ __launch_bounds__(256) void k_wle2(
    const float* __restrict__ hh, const float* __restrict__ agg,
    const float* __restrict__ W2, const float* __restrict__ b2,
    float* __restrict__ h2)
{
    __shared__ float sx[16][128];
    int tid=threadIdx.x; int r0=blockIdx.x*16;
#pragma unroll
    for (int k=0;k<8;++k){
        int lin=k*256+tid;
        size_t gidx=(size_t)r0*128+lin;
        sx[lin>>7][lin&127]=hh[gidx]+agg[gidx];
    }
    __syncthreads();
    int j=tid&127; int rb=(tid>>7)*8;
    float acc[8];
#pragma unroll
    for(int r=0;r<8;++r)acc[r]=0.f;
    for(int i=0;i<128;i+=4){
        float w0=W2[(i+0)*128+j], w1=W2[(i+1)*128+j];
        float w2v=W2[(i+2)*128+j], w3=W2[(i+3)*128+j];
#pragma unroll
        for(int r=0;r<8;++r){
            float4 f=*(const float4*)&sx[rb+r][i];
            acc[r]+=f.x*w0+f.y*w1+f.z*w2v+f.w*w3;
        }
    }
    float b=b2[j];
#pragma unroll
    for(int r=0;r<8;++r) h2[(size_t)(r0+rb+r)*128+j]=fmaxf(acc[r]+b,0.f);
}

// ---------------- edge scores as register-tiled GEMM, 8e x 16j per thread:
// 256 edges x 128 j per block; per k-step 6 b128 LDS reads feed 128 FMAs
// (0.75 B/MAC -> LDS pipe no longer the bottleneck).
#define KC 32
__global__ __launch_bounds__(256, 2) void k_edge6(
    const int* __restrict__ ei, const float* __restrict__ h2,
    const float* __restrict__ W3, const float* __restrict__ b3,
    const float* __restrict__ w4, const float* __restrict__ b4,
    float* __restrict__ sc)
{
    __shared__ float sE[KC*264];      // 33792 B, row stride 264
    __shared__ float sW[KC*128];      // 16384 B
    int tid = threadIdx.x;
    int bid = blockIdx.x;             // < TE/256 = 512
    int tb  = bid >> 6;               // timestep (64 blocks per t)
    int ein = (bid & 63)*256 + tid;   // this thread's staged edge
    int a = ei[tb*2*Ee + ein];
    int b = ei[tb*2*Ee + Ee + ein];
    const float4* __restrict__ pa = (const float4*)&h2[((size_t)(tb*Nn+a))*128];
    const float4* __restrict__ pb = (const float4*)&h2[((size_t)(tb*Nn+b))*128];

    int tx = tid & 7, ty = tid >> 3;  // tx: j-groups, ty: e-groups
    int e0 = ty*8;
    int jA = tx*4, jB = 32+tx*4, jC = 64+tx*4, jD = 96+tx*4;
    float4 b3A = *(const float4*)&b3[jA];
    float4 b3B = *(const float4*)&b3[jB];
    float4 b3C = *(const float4*)&b3[jC];
    float4 b3D = *(const float4*)&b3[jD];
    float4 w4A = *(const float4*)&w4[jA];
    float4 w4B = *(const float4*)&w4[jB];
    float4 w4C = *(const float4*)&w4[jC];
    float4 w4D = *(const float4*)&w4[jD];

    float acc[8][16];
#pragma unroll
    for (int i=0;i<8;++i)
#pragma unroll
        for (int j=0;j<16;++j) acc[i][j]=0.f;

    for (int c=0;c<4;++c){
        int k0 = c*KC;
        __syncthreads();
        // stage W chunk [KC][128] (linear, coalesced)
        {
            const float4* __restrict__ src = (const float4*)&W3[k0*128];
            float4* dst = (float4*)sW;
#pragma unroll
            for (int q=0;q<4;++q) dst[q*256+tid] = src[q*256+tid];
        }
        // stage ef chunk transposed: this thread fills column ein of sE for 32 k's
        {
            int kg = k0 >> 2;
#pragma unroll
            for (int q=0;q<8;++q){
                float4 x = pa[kg+q], y = pb[kg+q];
                sE[(q*4+0)*264 + tid] = x.x*y.x;
                sE[(q*4+1)*264 + tid] = x.y*y.y;
                sE[(q*4+2)*264 + tid] = x.z*y.z;
                sE[(q*4+3)*264 + tid] = x.w*y.w;
            }
        }
        __syncthreads();
#pragma unroll 8
        for (int kk=0;kk<KC;++kk){
            float4 ea = *(const float4*)&sE[kk*264 + e0];
            float4 eb = *(const float4*)&sE[kk*264 + e0 + 4];
            float4 wA = *(const float4*)&sW[kk*128 + jA];
            float4 wB = *(const float4*)&sW[kk*128 + jB];
            float4 wC = *(const float4*)&sW[kk*128 + jC];
            float4 wD = *(const float4*)&sW[kk*128 + jD];
            float ev0=ea.x, ev1=ea.y, ev2=ea.z, ev3=ea.w;
            float ev4=eb.x, ev5=eb.y, ev6=eb.z, ev7=eb.w;
#define ROW(i, ev) \
            acc[i][0]+=ev*wA.x;  acc[i][1]+=ev*wA.y;  acc[i][2]+=ev*wA.z;  acc[i][3]+=ev*wA.w; \
            acc[i][4]+=ev*wB.x;  acc[i][5]+=ev*wB.y;  acc[i][6]+=ev*wB.z;  acc[i][7]+=ev*wB.w; \
            acc[i][8]+=ev*wC.x;  acc[i][9]+=ev*wC.y;  acc[i][10]+=ev*wC.z; acc[i][11]+=ev*wC.w; \
            acc[i][12]+=ev*wD.x; acc[i][13]+=ev*wD.y; acc[i][14]+=ev*wD.z; acc[i][15]+=ev*wD.w;
            ROW(0,ev0) ROW(1,ev1) ROW(2,ev2) ROW(3,ev3)
            ROW(4,ev4) ROW(5,ev5) ROW(6,ev6) ROW(7,ev7)
#undef ROW
        }
    }
    // epilogue: p_e = sum_j relu(acc+b3)*w4, reduce across 8 tx lanes
    float b4v = b4[0];
#pragma unroll
    for (int i=0;i<8;++i){
        float p = fmaxf(acc[i][0]+b3A.x,0.f)*w4A.x
                + fmaxf(acc[i][1]+b3A.y,0.f)*w4A.y
                + fmaxf(acc[i][2]+b3A.z,0.f)*w4A.z
                + fmaxf(acc[i][3]+b3A.w,0.f)*w4A.w
                + fmaxf(acc[i][4]+b3B.x,0.f)*w4B.x
                + fmaxf(acc[i][5]+b3B.y,0.f)*w4B.y
                + fmaxf(acc[i][6]+b3B.z,0.f)*w4B.z
                + fmaxf(acc[i][7]+b3B.w,0.f)*w4B.w
                + fmaxf(acc[i][8]+b3C.x,0.f)*w4C.x
                + fmaxf(acc[i][9]+b3C.y,0.f)*w4C.y
                + fmaxf(acc[i][10]+b3C.z,0.f)*w4C.z
                + fmaxf(acc[i][11]+b3C.w,0.f)*w4C.w
                + fmaxf(acc[i][12]+b3D.x,0.f)*w4D.x
                + fmaxf(acc[i][13]+b3D.y,0.f)*w4D.y
                + fmaxf(acc[i][14]+b3D.z,0.f)*w4D.z
                + fmaxf(acc[i][15]+b3D.w,0.f)*w4D.w;
        p += __shfl_xor(p,1);
        p += __shfl_xor(p,2);
        p += __shfl_xor(p,4);
        if (tx==0) sc[bid*256 + e0 + i] = p + b4v;
    }
}

// ---------------- last-write-wins tag: tag[cell] = max(edge global idx + 1)
__global__ __launch_bounds__(256) void k_tag(const int* __restrict__ ei, int* __restrict__ tag)
{
    int g = blockIdx.x*256+threadIdx.x;        // < T*E
    int t = g>>14, e = g&(Ee-1);
    int a = ei[t*2*Ee + e], b = ei[t*2*Ee + Ee + e];
    atomicMax(&tag[t*NNc + a*Nn + b], g+1);
}

// ---------------- SSM recurrence (reads tag+sc directly, no dense buffer)
__global__ __launch_bounds__(256) void k_ssm2(
    const int* __restrict__ ei, const int* __restrict__ tag,
    const float* __restrict__ sc,
    const float* __restrict__ W_in, const float* __restrict__ conv_w,
    const float* __restrict__ conv_b, const float* __restrict__ dt_bias,
    const float* __restrict__ A_log, const float* __restrict__ D_skip,
    const float* __restrict__ W_out, float* __restrict__ out)
{
    __shared__ float scw[132], scb[33], swin[35];
    int tid = threadIdx.x;
    if (tid < 132) scw[tid] = conv_w[tid];
    if (tid < 33)  scb[tid] = conv_b[tid];
    if (tid < 35)  swin[tid] = W_in[tid];
    __syncthreads();

    int e = blockIdx.x*256 + tid;              // < E
    int a = ei[7*2*Ee + e], b = ei[7*2*Ee + Ee + e];
    int cell = a*Nn + b;
    float x[8];
#pragma unroll
    for (int t=0;t<8;++t){
        int tg = tag[t*NNc + cell];
        x[t] = (tg > 0) ? sc[tg-1] : 0.f;
    }

    float A    = -expf(A_log[0]);
    float dtb  = dt_bias[0];
    float dsk  = D_skip[0];
    float wout = W_out[0];
    float win_z = swin[0], win_dt = swin[34];

    float ssm[16];
#pragma unroll
    for (int q=0;q<16;++q) ssm[q]=0.f;
    float h0=0.f,h1=0.f,h2v=0.f;
    float y=0.f;
    for (int t=0;t<8;++t){
        float xt = x[t];
        float act[33];
#pragma unroll
        for (int c=0;c<33;++c){
            float s = h0*scw[c*4+0] + h1*scw[c*4+1] + h2v*scw[c*4+2] + xt*scw[c*4+3];
            float pre = swin[1+c]*s + scb[c];
            act[c] = pre / (1.f + expf(-pre));
        }
        float x_ = act[0];
        float dtr = xt*win_dt + dtb;
        float dt  = (dtr > 20.f) ? dtr : log1pf(expf(dtr));
        float dA  = expf(dt*A);
        float dx  = dt*x_;
        float yv = 0.f;
#pragma unroll
        for (int q=0;q<16;++q){
            ssm[q] = ssm[q]*dA + dx*act[1+q];
            yv += ssm[q]*act[17+q];
        }
        yv += dsk*x_;
        float z = xt*win_z;
        yv *= z / (1.f + expf(-z));
        y = yv;
        h0=h1; h1=h2v; h2v=xt;
    }
    out[cell] = y*wout;
}

extern "C" void kernel_launch(void* const* d_in, const int* in_sizes, int n_in,
                              void* d_out, int out_size, void* d_ws, size_t ws_size,
                              hipStream_t stream)
{
    const int*   ei    = (const int*)d_in[0];
    const float* ew    = (const float*)d_in[1];
    const float* feats = (const float*)d_in[2];
    const float* noise = (const float*)d_in[3];
    const float* Wp1=(const float*)d_in[4];  const float* bp1=(const float*)d_in[5];
    const float* Wp2=(const float*)d_in[6];  const float* bp2=(const float*)d_in[7];
    const float* W1 =(const float*)d_in[8];  const float* b1 =(const float*)d_in[9];
    const float* W2 =(const float*)d_in[10]; const float* b2 =(const float*)d_in[11];
    const float* W3 =(const float*)d_in[12]; const float* b3 =(const float*)d_in[13];
    const float* w4 =(const float*)d_in[14]; const float* b4 =(const float*)d_in[15];
    const float* W_in  =(const float*)d_in[16]; const float* conv_w=(const float*)d_in[17];
    const float* conv_b=(const float*)d_in[18]; const float* dt_bias=(const float*)d_in[19];
    const float* A_log =(const float*)d_in[20]; const float* D_skip=(const float*)d_in[21];
    const float* W_out =(const float*)d_in[22];

    float* out = (float*)d_out;
    float* ws  = (float*)d_ws;
    float* hh    = ws;                      // T*N*128  = 524288
    float* agg   = hh    + 524288;          // 524288
    float* h2    = agg   + 524288;          // 524288
    float* sc    = h2    + 524288;          // T*E      = 131072
    int*   tag   = (int*)(sc + 131072);     // T*N*N    = 2097152 ints
    int*   cnt    = tag + 2097152;          // T*N      = 4096 ints
    int*   bucket = cnt + TNr;              // T*N*CAP  = 524288 ints

    hipMemsetAsync(out, 0, (size_t)NNc*4,     stream);
    hipMemsetAsync(cnt, 0, (size_t)TNr*4,     stream);
    hipMemsetAsync(tag, 0, (size_t)2097152*4, stream);

    k_hist    <<<TE/256, 256, 0, stream>>>(ei, cnt, bucket);
    k_fp1     <<<TNr/16, 256, 0, stream>>>(feats, noise, Wp1, bp1, Wp2, bp2, W1, b1, hh);
    k_scatter2<<<TNr, 128, 0, stream>>>(ei, ew, hh, cnt, bucket, agg);
    k_wle2    <<<TNr/16, 256, 0, stream>>>(hh, agg, W2, b2, h2);
    k_edge6   <<<TE/256, 256, 0, stream>>>(ei, h2, W3, b3, w4, b4, sc);
    k_tag     <<<TE/256, 256, 0, stream>>>(ei, tag);
    k_ssm2    <<<Ee/256, 256, 0, stream>>>(ei, tag, sc, W_in, conv_w, conv_b,
                                           dt_bias, A_log, D_skip, W_out, out);
}